// Round 1
// baseline (44756.241 us; speedup 1.0000x reference)
//
#include <hip/hip_runtime.h>
#include <math.h>

// Problem constants (B, H, V, T from reference)
#define Bb 32
#define Hh 1024
#define Vv 32000
#define Tt 128
#define K2 2048   // 2*H

// ---------------------------------------------------------------------------
// K0: init hidden double-buffer phase 0 and dec_in tokens
// ---------------------------------------------------------------------------
__global__ __launch_bounds__(256) void init_kernel(
    const float* __restrict__ hidden,   // [2][B][H]
    const int* __restrict__ inputs,     // [B]
    float* __restrict__ h0,             // [2][B][H] (phase 0)
    int* __restrict__ dec_in)           // [B]
{
    int i = blockIdx.x * 256 + threadIdx.x;
    if (i < 2 * Bb * Hh) h0[i] = hidden[i];
    if (i < Bb) dec_in[i] = inputs[i];
}

// ---------------------------------------------------------------------------
// K1: one GRU step for both directions.
// One wave per (dir, b, i-group of 8). Each wave computes 8 output elements:
// 6 dot products of length 1024 each per element (x·w_ih rows, h·w_hh rows).
// Weight rows are read once per (b, i) but shared across the 8 i's per wave
// load-wise; x/h rows amortized over the 8 i's.
// ---------------------------------------------------------------------------
__global__ __launch_bounds__(256) void gru_step_kernel(
    const float* __restrict__ emb,
    const float* __restrict__ wih_f, const float* __restrict__ whh_f,
    const float* __restrict__ bih_f, const float* __restrict__ bhh_f,
    const float* __restrict__ wih_b, const float* __restrict__ whh_b,
    const float* __restrict__ bih_b, const float* __restrict__ bhh_b,
    const float* __restrict__ h_prev,   // [2][B][H]
    float* __restrict__ h_next,         // [2][B][H]
    const int* __restrict__ dec_in)
{
    const int wid  = (blockIdx.x * 256 + threadIdx.x) >> 6;  // 0..8191
    const int lane = threadIdx.x & 63;
    const int ig   = wid & 127;          // i-group (8 i's each)
    const int b    = (wid >> 7) & 31;
    const int dir  = wid >> 12;          // 0..1
    const int i0   = ig * 8;

    const float* wih = dir ? wih_b : wih_f;
    const float* whh = dir ? whh_b : whh_f;
    const float* bih = dir ? bih_b : bih_f;
    const float* bhh = dir ? bhh_b : bhh_f;

    const int token = dec_in[b];
    const float* x  = emb + (size_t)token * Hh;
    const float* hp = h_prev + ((size_t)dir * Bb + b) * Hh;

    // acc[ii][g]: g=0..2 -> x·w_ih rows (r,z,n); g=3..5 -> h·w_hh rows (r,z,n)
    float acc[8][6];
    #pragma unroll
    for (int ii = 0; ii < 8; ++ii)
        #pragma unroll
        for (int g = 0; g < 6; ++g) acc[ii][g] = 0.f;

    #pragma unroll
    for (int it = 0; it < 4; ++it) {
        const int k = (it * 64 + lane) * 4;
        const float4 xv = *(const float4*)(x + k);
        const float4 hv = *(const float4*)(hp + k);
        #pragma unroll
        for (int ii = 0; ii < 8; ++ii) {
            const int i = i0 + ii;
            const float4 wr = *(const float4*)(wih + (size_t)i * Hh + k);
            const float4 wz = *(const float4*)(wih + (size_t)(Hh + i) * Hh + k);
            const float4 wn = *(const float4*)(wih + (size_t)(2 * Hh + i) * Hh + k);
            const float4 vr = *(const float4*)(whh + (size_t)i * Hh + k);
            const float4 vz = *(const float4*)(whh + (size_t)(Hh + i) * Hh + k);
            const float4 vn = *(const float4*)(whh + (size_t)(2 * Hh + i) * Hh + k);
            acc[ii][0] += xv.x * wr.x + xv.y * wr.y + xv.z * wr.z + xv.w * wr.w;
            acc[ii][1] += xv.x * wz.x + xv.y * wz.y + xv.z * wz.z + xv.w * wz.w;
            acc[ii][2] += xv.x * wn.x + xv.y * wn.y + xv.z * wn.z + xv.w * wn.w;
            acc[ii][3] += hv.x * vr.x + hv.y * vr.y + hv.z * vr.z + hv.w * vr.w;
            acc[ii][4] += hv.x * vz.x + hv.y * vz.y + hv.z * vz.z + hv.w * vz.w;
            acc[ii][5] += hv.x * vn.x + hv.y * vn.y + hv.z * vn.z + hv.w * vn.w;
        }
    }

    // butterfly reduce each accumulator across 64 lanes
    #pragma unroll
    for (int ii = 0; ii < 8; ++ii)
        #pragma unroll
        for (int g = 0; g < 6; ++g) {
            float v = acc[ii][g];
            #pragma unroll
            for (int off = 32; off > 0; off >>= 1)
                v += __shfl_xor(v, off, 64);
            acc[ii][g] = v;
        }

    if (lane == 0) {
        #pragma unroll
        for (int ii = 0; ii < 8; ++ii) {
            const int i = i0 + ii;
            const float gr = acc[ii][0] + acc[ii][3] + bih[i] + bhh[i];
            const float gz = acc[ii][1] + acc[ii][4] + bih[Hh + i] + bhh[Hh + i];
            const float ghn = acc[ii][5] + bhh[2 * Hh + i];
            const float gin = acc[ii][2] + bih[2 * Hh + i];
            const float r = 1.f / (1.f + expf(-gr));
            const float z = 1.f / (1.f + expf(-gz));
            const float n = tanhf(gin + r * ghn);
            const float prev = hp[i];
            h_next[((size_t)dir * Bb + b) * Hh + i] = (1.f - z) * n + z * prev;
        }
    }
}

// ---------------------------------------------------------------------------
// K2: logits[b][v] = concat(h_f[b],h_b[b]) . w_out[v] + b_out[v]
// written directly into d_out[b][t][v].
// Block: 256 threads = 4 waves; wave kw owns K-quarter. Per-thread tile:
// 4 b's (tb+8i) x 8 v's. h staged in LDS (stride 260 -> conflict-free reads).
// Cross-kw partial sums reduced through LDS at the end.
// ---------------------------------------------------------------------------
#define KT 256
#define HS_STRIDE 260

__global__ __launch_bounds__(256) void logits_kernel(
    const float* __restrict__ h,        // [2][B][H] (current phase)
    const float* __restrict__ w_out,    // [V][2H]
    const float* __restrict__ b_out,    // [V]
    float* __restrict__ out,            // [B][T][V]
    const int t)
{
    __shared__ __align__(16) float hs[Bb * HS_STRIDE];   // 33280 B
    __shared__ __align__(16) float scr[3 * 64 * 32];     // 24576 B

    const int tid = threadIdx.x;
    const int kw  = tid >> 6;            // K quarter 0..3
    const int tb  = tid & 7;             // b group
    const int tv  = (tid >> 3) & 7;      // v group
    const int v0  = blockIdx.x * 64;

    float acc[4][8];
    #pragma unroll
    for (int i = 0; i < 4; ++i)
        #pragma unroll
        for (int j = 0; j < 8; ++j) acc[i][j] = 0.f;

    for (int kt = 0; kt < K2; kt += KT) {
        // stage h[all b][kt..kt+255] into LDS (dir0 rows for kt<H, dir1 after)
        const float* src = h + ((kt >= Hh) ? ((size_t)Bb * Hh + (size_t)(kt - Hh))
                                           : (size_t)kt);
        #pragma unroll
        for (int s = 0; s < 8; ++s) {
            const int f  = tid + 256 * s;      // 0..2047 float4 slots
            const int bb = f >> 6;
            const int kk = (f & 63) << 2;
            *(float4*)(&hs[bb * HS_STRIDE + kk]) =
                *(const float4*)(src + (size_t)bb * Hh + kk);
        }
        __syncthreads();

        const float* wbase = w_out + kt + kw * 64;
        #pragma unroll 2
        for (int kk = 0; kk < 64; kk += 4) {
            const int kl = kw * 64 + kk;
            float4 hv[4];
            #pragma unroll
            for (int i = 0; i < 4; ++i)
                hv[i] = *(const float4*)(&hs[(tb + 8 * i) * HS_STRIDE + kl]);
            #pragma unroll
            for (int j = 0; j < 8; ++j) {
                const float4 w4 =
                    *(const float4*)(wbase + (size_t)(v0 + tv * 8 + j) * K2 + kk);
                #pragma unroll
                for (int i = 0; i < 4; ++i) {
                    acc[i][j] = fmaf(hv[i].x, w4.x, acc[i][j]);
                    acc[i][j] = fmaf(hv[i].y, w4.y, acc[i][j]);
                    acc[i][j] = fmaf(hv[i].z, w4.z, acc[i][j]);
                    acc[i][j] = fmaf(hv[i].w, w4.w, acc[i][j]);
                }
            }
        }
        __syncthreads();
    }

    // reduce partial sums across the 4 K-quarters
    const int l = tid & 63;
    if (kw > 0) {
        float* p = &scr[(size_t)((kw - 1) * 64 + l) * 32];
        #pragma unroll
        for (int i = 0; i < 4; ++i)
            #pragma unroll
            for (int j = 0; j < 8; ++j) p[i * 8 + j] = acc[i][j];
    }
    __syncthreads();
    if (kw == 0) {
        #pragma unroll
        for (int q = 0; q < 3; ++q) {
            const float* p = &scr[(size_t)(q * 64 + l) * 32];
            #pragma unroll
            for (int i = 0; i < 4; ++i)
                #pragma unroll
                for (int j = 0; j < 8; ++j) acc[i][j] += p[i * 8 + j];
        }
        const int v = v0 + tv * 8;
        const float4 bo0 = *(const float4*)(b_out + v);
        const float4 bo1 = *(const float4*)(b_out + v + 4);
        #pragma unroll
        for (int i = 0; i < 4; ++i) {
            const int bb = tb + 8 * i;
            float* o = out + ((size_t)bb * Tt + t) * Vv + v;
            float4 r0 = make_float4(acc[i][0] + bo0.x, acc[i][1] + bo0.y,
                                    acc[i][2] + bo0.z, acc[i][3] + bo0.w);
            float4 r1 = make_float4(acc[i][4] + bo1.x, acc[i][5] + bo1.y,
                                    acc[i][6] + bo1.z, acc[i][7] + bo1.w);
            *(float4*)o = r0;
            *(float4*)(o + 4) = r1;
        }
    }
}

// ---------------------------------------------------------------------------
// K3: per batch row: max+argmax, sumexp, in-place log-softmax, next token.
// One block per b. Argmax tie-break: lowest index (matches jnp.argmax).
// ---------------------------------------------------------------------------
__global__ __launch_bounds__(256) void softmax_kernel(
    float* __restrict__ out,            // [B][T][V]
    int* __restrict__ dec_in,           // [B]
    const int t)
{
    const int b = blockIdx.x;
    float* row = out + ((size_t)b * Tt + t) * Vv;
    const int tid = threadIdx.x;
    const int wave = tid >> 6;

    __shared__ float sm[4];
    __shared__ int   si[4];
    __shared__ float ss[4];
    __shared__ float bc[2];   // [0]=max, [1]=lse
    __shared__ int   bi[1];

    // pass 1: max + argmax (first-index wins)
    float m = -INFINITY;
    int idx = 0x7fffffff;
    for (int v = tid; v < Vv; v += 256) {
        const float xv = row[v];
        if (xv > m) { m = xv; idx = v; }
    }
    #pragma unroll
    for (int off = 32; off > 0; off >>= 1) {
        const float om = __shfl_xor(m, off, 64);
        const int   oi = __shfl_xor(idx, off, 64);
        if (om > m || (om == m && oi < idx)) { m = om; idx = oi; }
    }
    if ((tid & 63) == 0) { sm[wave] = m; si[wave] = idx; }
    __syncthreads();
    if (tid == 0) {
        #pragma unroll
        for (int w = 1; w < 4; ++w)
            if (sm[w] > m || (sm[w] == m && si[w] < idx)) { m = sm[w]; idx = si[w]; }
        bc[0] = m;
        bi[0] = idx;
    }
    __syncthreads();
    m = bc[0];

    // pass 2: sum of exp
    float s = 0.f;
    for (int v = tid; v < Vv; v += 256) s += expf(row[v] - m);
    #pragma unroll
    for (int off = 32; off > 0; off >>= 1) s += __shfl_xor(s, off, 64);
    if ((tid & 63) == 0) ss[wave] = s;
    __syncthreads();
    if (tid == 0) bc[1] = m + logf(ss[0] + ss[1] + ss[2] + ss[3]);
    __syncthreads();
    const float lse = bc[1];

    // pass 3: subtract lse in place
    for (int v = tid; v < Vv; v += 256) row[v] -= lse;

    if (tid == 0) dec_in[b] = bi[0];
}

// ---------------------------------------------------------------------------
extern "C" void kernel_launch(void* const* d_in, const int* in_sizes, int n_in,
                              void* d_out, int out_size, void* d_ws, size_t ws_size,
                              hipStream_t stream) {
    (void)in_sizes; (void)n_in; (void)out_size; (void)ws_size;
    const int*   inputs = (const int*)d_in[0];
    const float* hidden = (const float*)d_in[1];
    const float* emb    = (const float*)d_in[2];
    const float* wih_f  = (const float*)d_in[3];
    const float* whh_f  = (const float*)d_in[4];
    const float* bih_f  = (const float*)d_in[5];
    const float* bhh_f  = (const float*)d_in[6];
    const float* wih_b  = (const float*)d_in[7];
    const float* whh_b  = (const float*)d_in[8];
    const float* bih_b  = (const float*)d_in[9];
    const float* bhh_b  = (const float*)d_in[10];
    const float* w_out  = (const float*)d_in[11];
    const float* b_out  = (const float*)d_in[12];
    float* out = (float*)d_out;

    // workspace layout: 2 phases x [2][B][H] floats, then dec_in ints
    float* hbuf = (float*)d_ws;
    int* dec_in = (int*)((char*)d_ws + (size_t)2 * 2 * Bb * Hh * sizeof(float));
    float* h_ph[2] = { hbuf, hbuf + (size_t)2 * Bb * Hh };

    init_kernel<<<256, 256, 0, stream>>>(hidden, inputs, h_ph[0], dec_in);

    for (int t = 0; t < Tt; ++t) {
        float* hp = h_ph[t & 1];
        float* hn = h_ph[(t + 1) & 1];
        gru_step_kernel<<<2048, 256, 0, stream>>>(
            emb, wih_f, whh_f, bih_f, bhh_f,
            wih_b, whh_b, bih_b, bhh_b, hp, hn, dec_in);
        logits_kernel<<<Vv / 64, 256, 0, stream>>>(hn, w_out, b_out, out, t);
        softmax_kernel<<<Bb, 256, 0, stream>>>(out, dec_in, t);
    }
}